// Round 1
// baseline (516.822 us; speedup 1.0000x reference)
//
#include <hip/hip_runtime.h>
#include <hip/hip_bf16.h>
#include <math.h>

// Problem constants
constexpr int NB = 256;     // batch
constexpr int NL = 50;      // seq len
constexpr int ND = 128;     // dim
constexpr int NK = 4;       // interests
constexpr int NVOC = 50000; // vocab
constexpr int NVm1 = 49999; // V-1
constexpr int NPAD = 50048; // N padded to multiple of 128 (391*128)
constexpr int ROWS = NB * NL; // 12800
constexpr int MROWS = NB * NK; // 1024 (rows of select, b-major: row = b*4+k)

typedef __bf16 bf16x8 __attribute__((ext_vector_type(8)));
typedef float f32x4 __attribute__((ext_vector_type(4)));

__device__ __forceinline__ float sigm_fast(float x) { return 1.0f / (1.0f + __expf(-x)); }
__device__ __forceinline__ float sigm_prec(float x) { return 1.0f / (1.0f + expf(-x)); }

// ---------------- K1: hs (masked mean over L) + lens ----------------
__global__ void k_hs_lens(const float* __restrict__ hidden, const int* __restrict__ mask,
                          float* __restrict__ hs, float* __restrict__ lens) {
    int b = blockIdx.x;
    int d = threadIdx.x; // 128
    float acc = 0.f, msum = 0.f;
    for (int l = 0; l < NL; ++l) {
        float mv = (float)mask[b * NL + l];
        acc += hidden[((size_t)b * NL + l) * ND + d] * mv;
        msum += mv;
    }
    hs[b * ND + d] = acc / msum;
    if (d == 0) lens[b] = msum - 5.0f; // LENGTH=5
}

// ---------------- K2: generic rowvec @ [128x128] matrix ----------------
// out[r,d] = sum_j rows[r,j] * mat[j*128+d]
__global__ void k_rowmat(const float* __restrict__ rows, const float* __restrict__ mat,
                         float* __restrict__ outp) {
    int r = blockIdx.x;
    int d = threadIdx.x; // 128
    __shared__ float s[ND];
    s[d] = rows[r * ND + d];
    __syncthreads();
    float acc = 0.f;
#pragma unroll 8
    for (int j = 0; j < ND; ++j) acc += s[j] * mat[j * ND + d];
    outp[r * ND + d] = acc;
}

// ---------------- K3: nh = tanh(posPart + X@W1h), att = tanh(hsW1 + X@attW2), alpha ----------------
// 32 rows per block, 256 threads
__global__ __launch_bounds__(256) void k_nh_att(
    const float* __restrict__ hidden, const float* __restrict__ w1,
    const float* __restrict__ att_w2, const float* __restrict__ att_v,
    const float* __restrict__ posPart, const float* __restrict__ hsW1,
    float* __restrict__ nh_out, float* __restrict__ alpha_out) {
    constexpr int R = 32;
    __shared__ float X[R * ND];       // 16 KB
    __shared__ float ATT[R * 132];    // padded rows (+4) to break bank conflicts
    int row0 = blockIdx.x * R;
    int tid = threadIdx.x;
    for (int i = tid; i < R * ND; i += 256) X[i] = hidden[(size_t)row0 * ND + i];
    __syncthreads();
    int d = tid & 127;
    int rg = tid >> 7; // 0/1 -> rows [rg*16, rg*16+16)
    float accN[16], accA[16];
#pragma unroll
    for (int r = 0; r < 16; ++r) { accN[r] = 0.f; accA[r] = 0.f; }
    for (int j = 0; j < ND; ++j) {
        float w1v = w1[(ND + j) * ND + d];   // lower half of w1 (hidden part)
        float awv = att_w2[j * ND + d];
#pragma unroll
        for (int r = 0; r < 16; ++r) {
            float x = X[(rg * 16 + r) * ND + j];
            accN[r] += x * w1v;
            accA[r] += x * awv;
        }
    }
#pragma unroll
    for (int r = 0; r < 16; ++r) {
        int row = row0 + rg * 16 + r;
        int b = row / NL;
        int l = row - b * NL;
        float nhv = tanhf(posPart[l * ND + d] + accN[r]);
        float atv = tanhf(hsW1[b * ND + d] + accA[r]);
        nh_out[(size_t)row * ND + d] = nhv;
        ATT[(rg * 16 + r) * 132 + d] = atv;
    }
    __syncthreads();
    // alpha: 32 rows x 4 k, one thread each (t<128)
    if (tid < 128) {
        int rl = tid >> 2;  // 0..31
        int k = tid & 3;
        float acc = 0.f;
        for (int dd = 0; dd < ND; ++dd) acc += ATT[rl * 132 + dd] * att_v[dd * NK + k];
        alpha_out[(size_t)(row0 + rl) * NK + k] = sigm_fast(acc);
    }
}

// ---------------- K4: g = sigmoid(NH @ glu1_w + b); beta[row,k]=sum_d g[k*128+d]*w2[d,k] * (0.5+alpha)*m ----------------
// 16 rows per block, 256 threads (each thread: cols tid and tid+256)
__global__ __launch_bounds__(256) void k_glu_beta(
    const float* __restrict__ nh, const float* __restrict__ glu1_w,
    const float* __restrict__ glu1_b, const float* __restrict__ w2,
    const float* __restrict__ alpha, const int* __restrict__ mask,
    float* __restrict__ beta_out) {
    constexpr int R = 16;
    __shared__ float NHs[R * ND];    // 8 KB
    __shared__ float P[R * 513];     // padded 512+1
    int row0 = blockIdx.x * R;
    int tid = threadIdx.x;
    for (int i = tid; i < R * ND; i += 256) NHs[i] = nh[(size_t)row0 * ND + i];
    __syncthreads();
    float acc0[R], acc1[R];
#pragma unroll
    for (int r = 0; r < R; ++r) { acc0[r] = 0.f; acc1[r] = 0.f; }
    int c0 = tid, c1 = tid + 256;
    for (int j = 0; j < ND; ++j) {
        float g0 = glu1_w[j * 512 + c0];
        float g1 = glu1_w[j * 512 + c1];
#pragma unroll
        for (int r = 0; r < R; ++r) {
            float x = NHs[r * ND + j];
            acc0[r] += x * g0;
            acc1[r] += x * g1;
        }
    }
    float bb0 = glu1_b[c0], bb1 = glu1_b[c1];
    float w20 = w2[(c0 & 127) * NK + (c0 >> 7)];
    float w21 = w2[(c1 & 127) * NK + (c1 >> 7)];
#pragma unroll
    for (int r = 0; r < R; ++r) {
        P[r * 513 + c0] = sigm_fast(acc0[r] + bb0) * w20;
        P[r * 513 + c1] = sigm_fast(acc1[r] + bb1) * w21;
    }
    __syncthreads();
    if (tid < 64) {
        int r = tid >> 2;
        int k = tid & 3;
        float s = 0.f;
        for (int dd = 0; dd < ND; ++dd) s += P[r * 513 + k * ND + dd];
        int row = row0 + r;
        float mv = (float)mask[row];
        float a = alpha[(size_t)row * NK + k];
        beta_out[(size_t)row * NK + k] = s * (0.5f + a) * mv;
    }
}

// ---------------- K5: per-b loss prep (normalize over L, Gram, sim, sigmoid) ----------------
__global__ void k_loss_b(const float* __restrict__ beta, const float* __restrict__ lens,
                         float* __restrict__ lossb) {
    int b = blockIdx.x;
    int t = threadIdx.x; // 64 (one wave)
    float bk[NK] = {0.f, 0.f, 0.f, 0.f};
    if (t < NL) {
#pragma unroll
        for (int k = 0; k < NK; ++k) bk[k] = beta[((size_t)b * NL + t) * NK + k];
    }
    float nb[NK];
#pragma unroll
    for (int k = 0; k < NK; ++k) {
        float v = bk[k] * bk[k];
        for (int off = 32; off >= 1; off >>= 1) v += __shfl_xor(v, off);
        nb[k] = bk[k] / fmaxf(sqrtf(v), 1e-12f);
    }
    float sim = 0.f;
#pragma unroll
    for (int i = 0; i < NK; ++i) {
#pragma unroll
        for (int j = 0; j < NK; ++j) {
            if (j > i) {
                float p = nb[i] * nb[j];
                for (int off = 32; off >= 1; off >>= 1) p += __shfl_xor(p, off);
                sim += fabsf(p);
            }
        }
    }
    sim *= (2.0f / (NK * (NK - 1)));
    if (t == 0) lossb[b] = sigm_prec(sim * lens[b]);
}

__global__ void k_loss_red(const float* __restrict__ lossb, float* __restrict__ out_scalar) {
    __shared__ float red[4];
    int t = threadIdx.x; // 256
    float v = lossb[t];
    for (int off = 32; off >= 1; off >>= 1) v += __shfl_xor(v, off);
    if ((t & 63) == 0) red[t >> 6] = v;
    __syncthreads();
    if (t == 0) out_scalar[0] = (red[0] + red[1] + red[2] + red[3]) * 0.01f; // BETA
}

// ---------------- K6: select[b*4+k, d] = sum_l beta[b,l,k]*hidden[b,l,d]  (bf16 out) ----------------
__global__ void k_select(const float* __restrict__ beta, const float* __restrict__ hidden,
                         __hip_bfloat16* __restrict__ selb) {
    int b = blockIdx.x;
    int d = threadIdx.x; // 128
    float acc[NK] = {0.f, 0.f, 0.f, 0.f};
    for (int l = 0; l < NL; ++l) {
        float h = hidden[((size_t)b * NL + l) * ND + d];
        const float* bp = &beta[((size_t)b * NL + l) * NK];
        acc[0] += bp[0] * h;
        acc[1] += bp[1] * h;
        acc[2] += bp[2] * h;
        acc[3] += bp[3] * h;
    }
#pragma unroll
    for (int k = 0; k < NK; ++k)
        selb[((size_t)b * NK + k) * ND + d] = __float2bfloat16(acc[k]);
}

// ---------------- K7: bnorm rows (emb[1:] L2-normalized) -> bf16, padded rows zeroed ----------------
__global__ void k_bnorm(const float* __restrict__ emb, __hip_bfloat16* __restrict__ bn) {
    int v = blockIdx.x * 2 + (threadIdx.x >> 7);
    int j = threadIdx.x & 127;
    __shared__ float red[4];
    float x = 0.f;
    if (v < NVm1) x = emb[((size_t)v + 1) * ND + j];
    float ss = x * x;
    for (int off = 32; off >= 1; off >>= 1) ss += __shfl_xor(ss, off);
    int w = threadIdx.x >> 6;
    if ((threadIdx.x & 63) == 0) red[w] = ss;
    __syncthreads();
    float tot = (threadIdx.x < 128) ? (red[0] + red[1]) : (red[2] + red[3]);
    float rn = 1.f / fmaxf(sqrtf(tot), 1e-12f);
    bn[(size_t)v * ND + j] = __float2bfloat16(x * rn);
}

// ---------------- K8: big GEMM  C[1024,NPAD] = selb @ bn^T, bf16 MFMA, fused max-over-k ----------------
// rows: m = b*4 + k.  Block tile 128x128, 4 waves in 2x2, each wave 4x4 subtiles of 16x16.
__global__ __launch_bounds__(256) void k_gemm(
    const __hip_bfloat16* __restrict__ selb, const __hip_bfloat16* __restrict__ bn,
    float* __restrict__ scores, float* __restrict__ maxs) {
    int bn0 = blockIdx.x * 128;
    int bm0 = blockIdx.y * 128;
    int wave = threadIdx.x >> 6;
    int lane = threadIdx.x & 63;
    int l16 = lane & 15;
    int quad = lane >> 4;
    int m_off = bm0 + (wave >> 1) * 64;
    int n_off = bn0 + (wave & 1) * 64;

    f32x4 acc[4][4];
#pragma unroll
    for (int mi = 0; mi < 4; ++mi)
#pragma unroll
        for (int ni = 0; ni < 4; ++ni) acc[mi][ni] = (f32x4){0.f, 0.f, 0.f, 0.f};

    const bf16x8* A = reinterpret_cast<const bf16x8*>(selb);
    const bf16x8* Bv = reinterpret_cast<const bf16x8*>(bn);
    // row stride in bf16x8 units = 128/8 = 16
#pragma unroll
    for (int kk = 0; kk < 4; ++kk) {
        int koff = kk * 4 + quad; // elem offset kk*32 + quad*8, in vec8 units
        bf16x8 afr[4], bfr[4];
#pragma unroll
        for (int mi = 0; mi < 4; ++mi)
            afr[mi] = A[(size_t)(m_off + mi * 16 + l16) * 16 + koff];
#pragma unroll
        for (int ni = 0; ni < 4; ++ni)
            bfr[ni] = Bv[(size_t)(n_off + ni * 16 + l16) * 16 + koff];
#pragma unroll
        for (int mi = 0; mi < 4; ++mi)
#pragma unroll
            for (int ni = 0; ni < 4; ++ni)
                acc[mi][ni] = __builtin_amdgcn_mfma_f32_16x16x32_bf16(
                    afr[mi], bfr[ni], acc[mi][ni], 0, 0, 0);
    }

    // Epilogue: C layout col=lane&15, row=quad*4+reg. Rows are b*4+k -> reg==k, b = m_base/4+quad.
#pragma unroll
    for (int mi = 0; mi < 4; ++mi) {
        int m_base = m_off + mi * 16;
        int bidx = (m_base >> 2) + quad;
#pragma unroll
        for (int ni = 0; ni < 4; ++ni) {
            int n = n_off + ni * 16 + l16;
            if (n < NVm1) {
                float mx = acc[mi][ni][0];
#pragma unroll
                for (int r = 0; r < 4; ++r) {
                    float val = acc[mi][ni][r];
                    scores[(size_t)r * NB * NVm1 + (size_t)bidx * NVm1 + n] = val;
                    mx = fmaxf(mx, val);
                }
                maxs[(size_t)bidx * NVm1 + n] = mx;
            }
        }
    }
}

extern "C" void kernel_launch(void* const* d_in, const int* in_sizes, int n_in,
                              void* d_out, int out_size, void* d_ws, size_t ws_size,
                              hipStream_t stream) {
    const float* hidden  = (const float*)d_in[0];
    const int*   mask    = (const int*)d_in[1];
    const float* pos_emb = (const float*)d_in[2];
    const float* w1      = (const float*)d_in[3];
    const float* w2      = (const float*)d_in[4];
    const float* glu1_w  = (const float*)d_in[5];
    const float* glu1_b  = (const float*)d_in[6];
    const float* att_w1  = (const float*)d_in[7];
    const float* att_w2  = (const float*)d_in[8];
    const float* att_v   = (const float*)d_in[9];
    const float* emb     = (const float*)d_in[10];

    float* out      = (float*)d_out;
    float* max_out  = out;                                   // [B, NVm1]
    float* loss_out = out + (size_t)NB * NVm1;               // scalar
    float* scores   = out + (size_t)NB * NVm1 + 1;           // [K, B, NVm1]

    char* w = (char*)d_ws;
    auto alloc = [&](size_t bytes) {
        char* p = w;
        w += (bytes + 255) & ~(size_t)255;
        return p;
    };
    float* posPart = (float*)alloc((size_t)NL * ND * 4);
    float* hs      = (float*)alloc((size_t)NB * ND * 4);
    float* lensv   = (float*)alloc((size_t)NB * 4);
    float* hsW1    = (float*)alloc((size_t)NB * ND * 4);
    float* nh      = (float*)alloc((size_t)ROWS * ND * 4);
    float* alphav  = (float*)alloc((size_t)ROWS * NK * 4);
    float* betav   = (float*)alloc((size_t)ROWS * NK * 4);
    float* lossb   = (float*)alloc((size_t)NB * 4);
    __hip_bfloat16* selb = (__hip_bfloat16*)alloc((size_t)MROWS * ND * 2);
    __hip_bfloat16* bnv  = (__hip_bfloat16*)alloc((size_t)NPAD * ND * 2);

    k_hs_lens<<<NB, 128, 0, stream>>>(hidden, mask, hs, lensv);
    k_rowmat<<<NL, 128, 0, stream>>>(pos_emb, w1, posPart);      // pos part uses w1 rows [0,128)
    k_rowmat<<<NB, 128, 0, stream>>>(hs, att_w1, hsW1);
    k_nh_att<<<ROWS / 32, 256, 0, stream>>>(hidden, w1, att_w2, att_v, posPart, hsW1, nh, alphav);
    k_glu_beta<<<ROWS / 16, 256, 0, stream>>>(nh, glu1_w, glu1_b, w2, alphav, mask, betav);
    k_loss_b<<<NB, 64, 0, stream>>>(betav, lensv, lossb);
    k_loss_red<<<1, 256, 0, stream>>>(lossb, loss_out);
    k_select<<<NB, 128, 0, stream>>>(betav, hidden, selb);
    k_bnorm<<<NPAD / 2, 256, 0, stream>>>(emb, bnv);
    k_gemm<<<dim3(NPAD / 128, MROWS / 128), 256, 0, stream>>>(selb, bnv, scores, max_out);
}

// Round 2
// 488.288 us; speedup vs baseline: 1.0584x; 1.0584x over previous
//
#include <hip/hip_runtime.h>
#include <hip/hip_bf16.h>
#include <math.h>

// Problem constants
constexpr int NB = 256;      // batch
constexpr int NL = 50;       // seq len
constexpr int ND = 128;      // dim
constexpr int NK = 4;        // interests
constexpr int NVm1 = 49999;  // V-1
constexpr int NPAD2 = 50176; // N padded to 392*128 (divisible by 512)
constexpr int ROWS = NB * NL;   // 12800
constexpr int MROWS = NB * NK;  // 1024 (rows of select, b-major: row = b*4+k)
constexpr int GEMM_NT = 4;      // n-tiles of 128 per block

typedef __bf16 bf16x8 __attribute__((ext_vector_type(8)));
typedef float f32x4 __attribute__((ext_vector_type(4)));

__device__ __forceinline__ float sigm_fast(float x) { return 1.0f / (1.0f + __expf(-x)); }
__device__ __forceinline__ float sigm_prec(float x) { return 1.0f / (1.0f + expf(-x)); }

__device__ __forceinline__ void gld_lds16(const void* g, void* l) {
    __builtin_amdgcn_global_load_lds(
        (const __attribute__((address_space(1))) void*)g,
        (__attribute__((address_space(3))) void*)l, 16, 0, 0);
}

// ---------------- K1: hs (masked mean over L); zero loss accumulator ----------------
__global__ void k_hs(const float* __restrict__ hidden, const int* __restrict__ mask,
                     float* __restrict__ hs, float* __restrict__ loss_out) {
    int b = blockIdx.x;
    int d = threadIdx.x; // 128
    float acc = 0.f, msum = 0.f;
    for (int l = 0; l < NL; ++l) {
        float mv = (float)mask[b * NL + l];
        acc += hidden[((size_t)b * NL + l) * ND + d] * mv;
        msum += mv;
    }
    hs[b * ND + d] = acc / msum;
    if (b == 0 && d == 0) loss_out[0] = 0.f; // later k_loss atomicAdds (stream-serial safe)
}

// ---------------- K2: fused rowvec @ [128x128] matrix for posPart and hsW1 ----------------
__global__ void k_rowmats(const float* __restrict__ pos_emb, const float* __restrict__ w1,
                          const float* __restrict__ hs, const float* __restrict__ att_w1,
                          float* __restrict__ posPart, float* __restrict__ hsW1) {
    int r = blockIdx.x; // 0..305
    int d = threadIdx.x; // 128
    const float *src, *mat;
    float* dst;
    if (r < NL) { src = pos_emb + (size_t)r * ND; mat = w1;     dst = posPart + (size_t)r * ND; }
    else        { int b = r - NL; src = hs + (size_t)b * ND; mat = att_w1; dst = hsW1 + (size_t)b * ND; }
    __shared__ float s[ND];
    s[d] = src[d];
    __syncthreads();
    float acc = 0.f;
#pragma unroll 8
    for (int j = 0; j < ND; ++j) acc += s[j] * mat[j * ND + d];
    dst[d] = acc;
}

// ---------------- K3: nh = tanh(posPart + X@W1h), att = tanh(hsW1 + X@attW2), alpha ----------------
__global__ __launch_bounds__(256) void k_nh_att(
    const float* __restrict__ hidden, const float* __restrict__ w1,
    const float* __restrict__ att_w2, const float* __restrict__ att_v,
    const float* __restrict__ posPart, const float* __restrict__ hsW1,
    float* __restrict__ nh_out, float* __restrict__ alpha_out) {
    constexpr int R = 32;
    __shared__ float X[R * ND];       // 16 KB
    __shared__ float ATT[R * 132];    // padded rows (+4) to break bank conflicts
    int row0 = blockIdx.x * R;
    int tid = threadIdx.x;
    for (int i = tid; i < R * ND; i += 256) X[i] = hidden[(size_t)row0 * ND + i];
    __syncthreads();
    int d = tid & 127;
    int rg = tid >> 7; // 0/1 -> rows [rg*16, rg*16+16)
    float accN[16], accA[16];
#pragma unroll
    for (int r = 0; r < 16; ++r) { accN[r] = 0.f; accA[r] = 0.f; }
    const float4* Xv = (const float4*)X; // row stride 32 float4
    for (int j4 = 0; j4 < 32; ++j4) {
        float w1v[4], awv[4];
#pragma unroll
        for (int u = 0; u < 4; ++u) {
            int j = j4 * 4 + u;
            w1v[u] = w1[(ND + j) * ND + d];   // lower half of w1 (hidden part)
            awv[u] = att_w2[j * ND + d];
        }
#pragma unroll
        for (int r = 0; r < 16; ++r) {
            float4 xv = Xv[(rg * 16 + r) * 32 + j4];
            accN[r] = fmaf(xv.w, w1v[3], fmaf(xv.z, w1v[2], fmaf(xv.y, w1v[1], fmaf(xv.x, w1v[0], accN[r]))));
            accA[r] = fmaf(xv.w, awv[3], fmaf(xv.z, awv[2], fmaf(xv.y, awv[1], fmaf(xv.x, awv[0], accA[r]))));
        }
    }
#pragma unroll
    for (int r = 0; r < 16; ++r) {
        int row = row0 + rg * 16 + r;
        int b = row / NL;
        int l = row - b * NL;
        float nhv = tanhf(posPart[l * ND + d] + accN[r]);
        float atv = tanhf(hsW1[b * ND + d] + accA[r]);
        nh_out[(size_t)row * ND + d] = nhv;
        ATT[(rg * 16 + r) * 132 + d] = atv;
    }
    __syncthreads();
    if (tid < 128) {
        int rl = tid >> 2;  // 0..31
        int k = tid & 3;
        float acc = 0.f;
        for (int dd = 0; dd < ND; ++dd) acc += ATT[rl * 132 + dd] * att_v[dd * NK + k];
        alpha_out[(size_t)(row0 + rl) * NK + k] = sigm_fast(acc);
    }
}

// ---------------- K4: g = sigmoid(NH @ glu1_w + b); beta fold ----------------
__global__ __launch_bounds__(256) void k_glu_beta(
    const float* __restrict__ nh, const float* __restrict__ glu1_w,
    const float* __restrict__ glu1_b, const float* __restrict__ w2,
    const float* __restrict__ alpha, const int* __restrict__ mask,
    float* __restrict__ beta_out) {
    constexpr int R = 16;
    __shared__ float NHs[R * ND];    // 8 KB
    __shared__ float P[R * 513];     // padded 512+1
    int row0 = blockIdx.x * R;
    int tid = threadIdx.x;
    for (int i = tid; i < R * ND; i += 256) NHs[i] = nh[(size_t)row0 * ND + i];
    __syncthreads();
    float acc0[R], acc1[R];
#pragma unroll
    for (int r = 0; r < R; ++r) { acc0[r] = 0.f; acc1[r] = 0.f; }
    int c0 = tid, c1 = tid + 256;
    const float4* Nv = (const float4*)NHs; // row stride 32 float4
    for (int j4 = 0; j4 < 32; ++j4) {
        float g0v[4], g1v[4];
#pragma unroll
        for (int u = 0; u < 4; ++u) {
            int j = j4 * 4 + u;
            g0v[u] = glu1_w[j * 512 + c0];
            g1v[u] = glu1_w[j * 512 + c1];
        }
#pragma unroll
        for (int r = 0; r < R; ++r) {
            float4 xv = Nv[r * 32 + j4];
            acc0[r] = fmaf(xv.w, g0v[3], fmaf(xv.z, g0v[2], fmaf(xv.y, g0v[1], fmaf(xv.x, g0v[0], acc0[r]))));
            acc1[r] = fmaf(xv.w, g1v[3], fmaf(xv.z, g1v[2], fmaf(xv.y, g1v[1], fmaf(xv.x, g1v[0], acc1[r]))));
        }
    }
    float bb0 = glu1_b[c0], bb1 = glu1_b[c1];
    float w20 = w2[(c0 & 127) * NK + (c0 >> 7)];
    float w21 = w2[(c1 & 127) * NK + (c1 >> 7)];
#pragma unroll
    for (int r = 0; r < R; ++r) {
        P[r * 513 + c0] = sigm_fast(acc0[r] + bb0) * w20;
        P[r * 513 + c1] = sigm_fast(acc1[r] + bb1) * w21;
    }
    __syncthreads();
    if (tid < 64) {
        int r = tid >> 2;
        int k = tid & 3;
        float s = 0.f;
        for (int dd = 0; dd < ND; ++dd) s += P[r * 513 + k * ND + dd];
        int row = row0 + r;
        float mv = (float)mask[row];
        float a = alpha[(size_t)row * NK + k];
        beta_out[(size_t)row * NK + k] = s * (0.5f + a) * mv;
    }
}

// ---------------- K5: loss (lens inline, atomic accumulate) ----------------
__global__ void k_loss(const float* __restrict__ beta, const int* __restrict__ mask,
                       float* __restrict__ loss_out) {
    int b = blockIdx.x;
    int t = threadIdx.x; // 64 (one wave)
    float mv = (t < NL) ? (float)mask[b * NL + t] : 0.f;
    float msum = mv;
    for (int off = 32; off >= 1; off >>= 1) msum += __shfl_xor(msum, off);
    float lens = msum - 5.0f; // LENGTH=5
    float bk[NK] = {0.f, 0.f, 0.f, 0.f};
    if (t < NL) {
#pragma unroll
        for (int k = 0; k < NK; ++k) bk[k] = beta[((size_t)b * NL + t) * NK + k];
    }
    float nb[NK];
#pragma unroll
    for (int k = 0; k < NK; ++k) {
        float v = bk[k] * bk[k];
        for (int off = 32; off >= 1; off >>= 1) v += __shfl_xor(v, off);
        nb[k] = bk[k] / fmaxf(sqrtf(v), 1e-12f);
    }
    float sim = 0.f;
#pragma unroll
    for (int i = 0; i < NK; ++i) {
#pragma unroll
        for (int j = 0; j < NK; ++j) {
            if (j > i) {
                float p = nb[i] * nb[j];
                for (int off = 32; off >= 1; off >>= 1) p += __shfl_xor(p, off);
                sim += fabsf(p);
            }
        }
    }
    sim *= (2.0f / (NK * (NK - 1)));
    if (t == 0) atomicAdd(loss_out, sigm_prec(sim * lens) * 0.01f); // BETA
}

// ---------------- K6: fused select (bf16) + bnorm (bf16) ----------------
__global__ __launch_bounds__(256) void k_sel_bnorm(
    const float* __restrict__ beta, const float* __restrict__ hidden,
    const float* __restrict__ emb, __hip_bfloat16* __restrict__ selb,
    __hip_bfloat16* __restrict__ bnv) {
    int blk = blockIdx.x;
    int tid = threadIdx.x;
    if (blk < NPAD2 / 2) {
        // bnorm: rows emb[1:] L2-normalized -> bf16; padded rows -> 0
        int v = blk * 2 + (tid >> 7);
        int j = tid & 127;
        __shared__ float red[4];
        float x = 0.f;
        if (v < NVm1) x = emb[((size_t)v + 1) * ND + j];
        float ss = x * x;
        for (int off = 32; off >= 1; off >>= 1) ss += __shfl_xor(ss, off);
        int w = tid >> 6;
        if ((tid & 63) == 0) red[w] = ss;
        __syncthreads();
        float tot = (tid < 128) ? (red[0] + red[1]) : (red[2] + red[3]);
        float rn = 1.f / fmaxf(sqrtf(tot), 1e-12f);
        bnv[(size_t)v * ND + j] = __float2bfloat16(x * rn);
    } else {
        // select: selb[b*4+k, d] = sum_l beta[b,l,k]*hidden[b,l,d]; 2 b per block
        int b = (blk - NPAD2 / 2) * 2 + (tid >> 7);
        int d = tid & 127;
        float a0 = 0.f, a1 = 0.f, a2 = 0.f, a3 = 0.f;
        for (int l = 0; l < NL; ++l) {
            float h = hidden[((size_t)b * NL + l) * ND + d];
            const float* bp = &beta[((size_t)b * NL + l) * NK];
            a0 = fmaf(bp[0], h, a0);
            a1 = fmaf(bp[1], h, a1);
            a2 = fmaf(bp[2], h, a2);
            a3 = fmaf(bp[3], h, a3);
        }
        selb[((size_t)b * NK + 0) * ND + d] = __float2bfloat16(a0);
        selb[((size_t)b * NK + 1) * ND + d] = __float2bfloat16(a1);
        selb[((size_t)b * NK + 2) * ND + d] = __float2bfloat16(a2);
        selb[((size_t)b * NK + 3) * ND + d] = __float2bfloat16(a3);
    }
}

// ---------------- K7: big GEMM  C[1024,NPAD2] = selb @ bnv^T, LDS-staged bf16 MFMA ----------------
// Block: m-tile 128 (staged once), loop GEMM_NT n-tiles of 128. Swizzled LDS layout:
// chunk (row, c) in LDS holds global chunk (row, c ^ (row&7)) -> ds_read_b128 lands 2-way/bank (free).
__global__ __launch_bounds__(256) void k_gemm(
    const __hip_bfloat16* __restrict__ selb, const __hip_bfloat16* __restrict__ bn,
    float* __restrict__ scores, float* __restrict__ maxs) {
    __shared__ __hip_bfloat16 As[128 * 128]; // 32 KB
    __shared__ __hip_bfloat16 Bs[128 * 128]; // 32 KB
    int bm0 = blockIdx.y * 128;
    int nbase = blockIdx.x * (128 * GEMM_NT);
    int tid = threadIdx.x;
    int wave = tid >> 6, lane = tid & 63;
    int l16 = lane & 15, quad = lane >> 4;
    int m_loc = (wave >> 1) * 64;
    int n_loc = (wave & 1) * 64;

    // stage A (once per block): 128 rows x 256 B, 8 iterations of 4 KB
#pragma unroll
    for (int it = 0; it < 8; ++it) {
        int id = it * 256 + tid;           // 16-B chunk id
        int row = id >> 4, c = id & 15;
        int gc = c ^ (row & 7);            // swizzle in global source
        const char* g = (const char*)selb + ((size_t)(bm0 + row) * 16 + gc) * 16;
        char* l = (char*)As + (size_t)(it * 256 + wave * 64) * 16; // wave-uniform base
        gld_lds16(g, l);
    }

    const bf16x8* Av = (const bf16x8*)As;
    const bf16x8* Bv = (const bf16x8*)Bs;

    for (int nt = 0; nt < GEMM_NT; ++nt) {
        int bn0 = nbase + nt * 128;
#pragma unroll
        for (int it = 0; it < 8; ++it) {
            int id = it * 256 + tid;
            int row = id >> 4, c = id & 15;
            int gc = c ^ (row & 7);
            const char* g = (const char*)bn + ((size_t)(bn0 + row) * 16 + gc) * 16;
            char* l = (char*)Bs + (size_t)(it * 256 + wave * 64) * 16;
            gld_lds16(g, l);
        }
        __syncthreads(); // drains vmcnt (compiler emits full waitcnt before s_barrier)

        f32x4 acc[4][4];
#pragma unroll
        for (int mi = 0; mi < 4; ++mi)
#pragma unroll
            for (int ni = 0; ni < 4; ++ni) acc[mi][ni] = (f32x4){0.f, 0.f, 0.f, 0.f};

#pragma unroll
        for (int kk = 0; kk < 4; ++kk) {
            int ko = kk * 4 + quad;
            bf16x8 afr[4], bfr[4];
#pragma unroll
            for (int mi = 0; mi < 4; ++mi) {
                int row = m_loc + mi * 16 + l16;
                afr[mi] = Av[row * 16 + (ko ^ (row & 7))];
            }
#pragma unroll
            for (int ni = 0; ni < 4; ++ni) {
                int row = n_loc + ni * 16 + l16;
                bfr[ni] = Bv[row * 16 + (ko ^ (row & 7))];
            }
#pragma unroll
            for (int mi = 0; mi < 4; ++mi)
#pragma unroll
                for (int ni = 0; ni < 4; ++ni)
                    acc[mi][ni] = __builtin_amdgcn_mfma_f32_16x16x32_bf16(
                        afr[mi], bfr[ni], acc[mi][ni], 0, 0, 0);
        }

        // Epilogue: C layout col=lane&15, row=quad*4+reg; rows m=b*4+k -> reg==k
#pragma unroll
        for (int mi = 0; mi < 4; ++mi) {
            int m_base = bm0 + m_loc + mi * 16;
            int bidx = (m_base >> 2) + quad;
#pragma unroll
            for (int ni = 0; ni < 4; ++ni) {
                int n = bn0 + n_loc + ni * 16 + l16;
                if (n < NVm1) {
                    float mx = acc[mi][ni][0];
#pragma unroll
                    for (int r = 0; r < 4; ++r) {
                        float val = acc[mi][ni][r];
                        scores[(size_t)r * NB * NVm1 + (size_t)bidx * NVm1 + n] = val;
                        mx = fmaxf(mx, val);
                    }
                    maxs[(size_t)bidx * NVm1 + n] = mx;
                }
            }
        }
        __syncthreads(); // all waves done with Bs before next stage
    }
}

extern "C" void kernel_launch(void* const* d_in, const int* in_sizes, int n_in,
                              void* d_out, int out_size, void* d_ws, size_t ws_size,
                              hipStream_t stream) {
    const float* hidden  = (const float*)d_in[0];
    const int*   mask    = (const int*)d_in[1];
    const float* pos_emb = (const float*)d_in[2];
    const float* w1      = (const float*)d_in[3];
    const float* w2      = (const float*)d_in[4];
    const float* glu1_w  = (const float*)d_in[5];
    const float* glu1_b  = (const float*)d_in[6];
    const float* att_w1  = (const float*)d_in[7];
    // d_in[8] = att_w2, d_in[9] = att_v
    const float* att_w2  = (const float*)d_in[8];
    const float* att_v   = (const float*)d_in[9];
    const float* emb     = (const float*)d_in[10];

    float* out      = (float*)d_out;
    float* max_out  = out;                                   // [B, NVm1]
    float* loss_out = out + (size_t)NB * NVm1;               // scalar
    float* scores   = out + (size_t)NB * NVm1 + 1;           // [K, B, NVm1]

    char* w = (char*)d_ws;
    auto alloc = [&](size_t bytes) {
        char* p = w;
        w += (bytes + 255) & ~(size_t)255;
        return p;
    };
    float* posPart = (float*)alloc((size_t)NL * ND * 4);
    float* hs      = (float*)alloc((size_t)NB * ND * 4);
    float* hsW1    = (float*)alloc((size_t)NB * ND * 4);
    float* nh      = (float*)alloc((size_t)ROWS * ND * 4);
    float* alphav  = (float*)alloc((size_t)ROWS * NK * 4);
    float* betav   = (float*)alloc((size_t)ROWS * NK * 4);
    __hip_bfloat16* selb = (__hip_bfloat16*)alloc((size_t)MROWS * ND * 2);
    __hip_bfloat16* bnv  = (__hip_bfloat16*)alloc((size_t)NPAD2 * ND * 2);

    k_hs<<<NB, 128, 0, stream>>>(hidden, mask, hs, loss_out);
    k_rowmats<<<NL + NB, 128, 0, stream>>>(pos_emb, w1, hs, att_w1, posPart, hsW1);
    k_nh_att<<<ROWS / 32, 256, 0, stream>>>(hidden, w1, att_w2, att_v, posPart, hsW1, nh, alphav);
    k_glu_beta<<<ROWS / 16, 256, 0, stream>>>(nh, glu1_w, glu1_b, w2, alphav, mask, betav);
    k_loss<<<NB, 64, 0, stream>>>(betav, mask, loss_out);
    k_sel_bnorm<<<NPAD2 / 2 + NB / 2, 256, 0, stream>>>(betav, hidden, emb, selb, bnv);
    k_gemm<<<dim3(NPAD2 / (128 * GEMM_NT), MROWS / 128), 256, 0, stream>>>(selb, bnv, scores, max_out);
}

// Round 3
// 435.348 us; speedup vs baseline: 1.1871x; 1.1216x over previous
//
#include <hip/hip_runtime.h>
#include <hip/hip_bf16.h>
#include <math.h>

// Problem constants
constexpr int NB = 256;      // batch
constexpr int NL = 50;       // seq len
constexpr int ND = 128;      // dim
constexpr int NK = 4;        // interests
constexpr int NVm1 = 49999;  // V-1
constexpr int NPAD2 = 50176; // N padded to 392*128
constexpr int ROWS = NB * NL;   // 12800
constexpr int MROWS = NB * NK;  // 1024 (rows of select, b-major: row = b*4+k)
constexpr int GEMM_NT = 4;      // n-tiles of 128 per block in big GEMM
constexpr int MR = 64;          // rows per mega block

// prep kernel block ranges
constexpr int G_BN  = NPAD2 / 2;  // 25088 bnorm (2 rows/blk)
constexpr int G_HS  = NB / 2;     // 128 hs (2 b/blk)
constexpr int G_PP  = NL / 2;     // 25 posPart (2 rows/blk)
constexpr int G_XB  = ROWS * ND / 2048; // 800 Xb cast
constexpr int G_W1T = ND * ND / 256;    // 64
constexpr int G_AWT = ND * ND / 256;    // 64
constexpr int G_GLT = ND * 512 / 256;   // 256
constexpr int G_TOT = G_BN + G_HS + G_PP + G_XB + G_W1T + G_AWT + G_GLT;

typedef __bf16 bf16x8 __attribute__((ext_vector_type(8)));
typedef float f32x4 __attribute__((ext_vector_type(4)));

__device__ __forceinline__ float sigm_fast(float x) { return 1.0f / (1.0f + __expf(-x)); }
__device__ __forceinline__ float sigm_prec(float x) { return 1.0f / (1.0f + expf(-x)); }
__device__ __forceinline__ float fast_tanh(float x) {
    float xc = fminf(fmaxf(x, -15.f), 15.f);
    float e = __expf(2.f * xc);
    return (e - 1.f) / (e + 1.f);
}

__device__ __forceinline__ void gld_lds16(const void* g, void* l) {
    __builtin_amdgcn_global_load_lds(
        (const __attribute__((address_space(1))) void*)g,
        (__attribute__((address_space(3))) void*)l, 16, 0, 0);
}

// ---------------- K0: prep — bnorm, hs, posPart, Xb cast, weight transposes ----------------
__global__ __launch_bounds__(256) void k_prep(
    const float* __restrict__ hidden, const int* __restrict__ mask,
    const float* __restrict__ pos_emb, const float* __restrict__ w1,
    const float* __restrict__ att_w2, const float* __restrict__ glu1_w,
    const float* __restrict__ emb,
    float* __restrict__ hs, float* __restrict__ posPart,
    __hip_bfloat16* __restrict__ XbG, __hip_bfloat16* __restrict__ w1h_t,
    __hip_bfloat16* __restrict__ attw2_t, __hip_bfloat16* __restrict__ glu_t,
    __hip_bfloat16* __restrict__ bnv, float* __restrict__ loss_out) {
    __shared__ float sPP[2 * ND];
    __shared__ float red[4];
    int blk = blockIdx.x, tid = threadIdx.x;
    if (blk < G_BN) {
        // bnorm: rows emb[1:] L2-normalized -> bf16; padded rows -> 0
        int v = blk * 2 + (tid >> 7);
        int j = tid & 127;
        float x = 0.f;
        if (v < NVm1) x = emb[((size_t)v + 1) * ND + j];
        float ss = x * x;
        for (int off = 32; off >= 1; off >>= 1) ss += __shfl_xor(ss, off);
        if ((tid & 63) == 0) red[tid >> 6] = ss;
        __syncthreads();
        float tot = (tid < 128) ? (red[0] + red[1]) : (red[2] + red[3]);
        float rn = 1.f / fmaxf(sqrtf(tot), 1e-12f);
        bnv[(size_t)v * ND + j] = __float2bfloat16(x * rn);
    } else if (blk < G_BN + G_HS) {
        int b = (blk - G_BN) * 2 + (tid >> 7);
        int d = tid & 127;
        float acc = 0.f, msum = 0.f;
        for (int l = 0; l < NL; ++l) {
            float mv = (float)mask[b * NL + l];
            acc += hidden[((size_t)b * NL + l) * ND + d] * mv;
            msum += mv;
        }
        hs[b * ND + d] = acc / msum;
        if (blk == G_BN && tid == 0) loss_out[0] = 0.f;
    } else if (blk < G_BN + G_HS + G_PP) {
        int rel = blk - (G_BN + G_HS);
        int rl = tid >> 7, d = tid & 127;
        int r = rel * 2 + rl;
        sPP[rl * ND + d] = pos_emb[r * ND + d];
        __syncthreads();
        float acc = 0.f;
#pragma unroll 8
        for (int j = 0; j < ND; ++j) acc += sPP[rl * ND + j] * w1[j * ND + d]; // w1 upper half
        posPart[r * ND + d] = acc;
    } else if (blk < G_BN + G_HS + G_PP + G_XB) {
        int rel = blk - (G_BN + G_HS + G_PP);
        size_t base = (size_t)rel * 2048 + (size_t)tid * 8;
        float4 f0 = *(const float4*)&hidden[base];
        float4 f1 = *(const float4*)&hidden[base + 4];
        union { bf16x8 v; __hip_bfloat16 h[8]; } u;
        u.h[0] = __float2bfloat16(f0.x); u.h[1] = __float2bfloat16(f0.y);
        u.h[2] = __float2bfloat16(f0.z); u.h[3] = __float2bfloat16(f0.w);
        u.h[4] = __float2bfloat16(f1.x); u.h[5] = __float2bfloat16(f1.y);
        u.h[6] = __float2bfloat16(f1.z); u.h[7] = __float2bfloat16(f1.w);
        *(bf16x8*)&XbG[base] = u.v;
    } else if (blk < G_BN + G_HS + G_PP + G_XB + G_W1T) {
        int i = (blk - (G_BN + G_HS + G_PP + G_XB)) * 256 + tid;
        int d = i >> 7, j = i & 127;
        w1h_t[d * ND + j] = __float2bfloat16(w1[(ND + j) * ND + d]); // lower (hidden) half
    } else if (blk < G_BN + G_HS + G_PP + G_XB + G_W1T + G_AWT) {
        int i = (blk - (G_BN + G_HS + G_PP + G_XB + G_W1T)) * 256 + tid;
        int d = i >> 7, j = i & 127;
        attw2_t[d * ND + j] = __float2bfloat16(att_w2[j * ND + d]);
    } else {
        int i = (blk - (G_BN + G_HS + G_PP + G_XB + G_W1T + G_AWT)) * 256 + tid;
        int c = i >> 7, j = i & 127;
        glu_t[c * ND + j] = __float2bfloat16(glu1_w[j * 512 + c]);
    }
}

// ---------------- K1: mega — GEMM1(att,nh via MFMA) + alpha + GEMM2(glu) + beta ----------------
// Block: 64 rows, 4 waves; wave w owns rows [w*16, w*16+16). Swizzled LDS for glds tiles;
// padded LDS for NH (ds_write side). All accumulation fp32, operands bf16.
__global__ __launch_bounds__(256) void k_mega(
    const __hip_bfloat16* __restrict__ XbG, const __hip_bfloat16* __restrict__ w1h_t,
    const __hip_bfloat16* __restrict__ attw2_t, const __hip_bfloat16* __restrict__ glu_t,
    const float* __restrict__ hs, const float* __restrict__ att_w1,
    const float* __restrict__ att_v, const float* __restrict__ posPart,
    const float* __restrict__ glu1_b, const float* __restrict__ w2,
    const int* __restrict__ mask, float* __restrict__ beta_out) {
    __shared__ __hip_bfloat16 XbS[MR * ND];   // 16 KB swizzled
    __shared__ __hip_bfloat16 WS[ND * ND];    // 32 KB swizzled
    __shared__ __attribute__((aligned(16))) __hip_bfloat16 NHS[MR * 136]; // padded (+8)
    __shared__ float alphaS[MR * NK];
    __shared__ float hsW1S[3 * ND];
    int row0 = blockIdx.x * MR;
    int tid = threadIdx.x;
    int wave = tid >> 6, lane = tid & 63, l16 = lane & 15, quad = lane >> 4;
    int b0 = row0 / NL;

    // stage Xb tile (64 rows x 256B) + Watt tile (128 rows x 256B)
#pragma unroll
    for (int it = 0; it < 4; ++it) {
        int id = it * 256 + tid;
        int row = id >> 4, c = id & 15, gc = c ^ (row & 7);
        gld_lds16((const char*)XbG + ((size_t)(row0 + row) * 16 + gc) * 16,
                  (char*)XbS + (size_t)(it * 256 + wave * 64) * 16);
    }
#pragma unroll
    for (int it = 0; it < 8; ++it) {
        int id = it * 256 + tid;
        int row = id >> 4, c = id & 15, gc = c ^ (row & 7);
        gld_lds16((const char*)attw2_t + ((size_t)row * 16 + gc) * 16,
                  (char*)WS + (size_t)(it * 256 + wave * 64) * 16);
    }
    // hsW1S[bb][d] for the (up to) 3 b's this block touches
    for (int i = tid; i < 3 * ND; i += 256) {
        int bb = i >> 7, d = i & 127, b = b0 + bb;
        float acc = 0.f;
        if (b < NB) {
            for (int j = 0; j < ND; ++j) acc += hs[b * ND + j] * att_w1[j * ND + d];
        }
        hsW1S[i] = acc;
    }
    __syncthreads();

    const bf16x8* Xv = (const bf16x8*)XbS;
    const bf16x8* Wv = (const bf16x8*)WS;
    const bf16x8* Nv = (const bf16x8*)NHS; // row stride 17 (136 bf16)
    int arow = wave * 16 + l16;

    f32x4 acc8[8];
    // ---- GEMM1-att ----
#pragma unroll
    for (int ni = 0; ni < 8; ++ni) acc8[ni] = (f32x4){0.f, 0.f, 0.f, 0.f};
#pragma unroll
    for (int kk = 0; kk < 4; ++kk) {
        int ko = kk * 4 + quad;
        bf16x8 af = Xv[arow * 16 + (ko ^ (arow & 7))];
#pragma unroll
        for (int ni = 0; ni < 8; ++ni) {
            int n = ni * 16 + l16;
            bf16x8 bf = Wv[n * 16 + (ko ^ (n & 7))];
            acc8[ni] = __builtin_amdgcn_mfma_f32_16x16x32_bf16(af, bf, acc8[ni], 0, 0, 0);
        }
    }
    // epilogue: alpha[row][k] = sigmoid(sum_col tanh(hsW1+c) * att_v[col][k])
#pragma unroll
    for (int r = 0; r < 4; ++r) {
        int lrow = wave * 16 + quad * 4 + r;
        int grow = row0 + lrow;
        int bb = grow / NL - b0;
        float a0 = 0.f, a1 = 0.f, a2 = 0.f, a3 = 0.f;
#pragma unroll
        for (int ni = 0; ni < 8; ++ni) {
            int col = ni * 16 + l16;
            float atv = fast_tanh(hsW1S[bb * ND + col] + acc8[ni][r]);
            float4 av = *(const float4*)&att_v[col * 4];
            a0 += atv * av.x; a1 += atv * av.y; a2 += atv * av.z; a3 += atv * av.w;
        }
#pragma unroll
        for (int off = 1; off < 16; off <<= 1) {
            a0 += __shfl_xor(a0, off); a1 += __shfl_xor(a1, off);
            a2 += __shfl_xor(a2, off); a3 += __shfl_xor(a3, off);
        }
        if (l16 == 0) {
            alphaS[lrow * 4 + 0] = sigm_fast(a0);
            alphaS[lrow * 4 + 1] = sigm_fast(a1);
            alphaS[lrow * 4 + 2] = sigm_fast(a2);
            alphaS[lrow * 4 + 3] = sigm_fast(a3);
        }
    }
    __syncthreads(); // WS reads done
    // restage WS = w1h_t
#pragma unroll
    for (int it = 0; it < 8; ++it) {
        int id = it * 256 + tid;
        int row = id >> 4, c = id & 15, gc = c ^ (row & 7);
        gld_lds16((const char*)w1h_t + ((size_t)row * 16 + gc) * 16,
                  (char*)WS + (size_t)(it * 256 + wave * 64) * 16);
    }
    __syncthreads();
    // ---- GEMM1-nh ----
#pragma unroll
    for (int ni = 0; ni < 8; ++ni) acc8[ni] = (f32x4){0.f, 0.f, 0.f, 0.f};
#pragma unroll
    for (int kk = 0; kk < 4; ++kk) {
        int ko = kk * 4 + quad;
        bf16x8 af = Xv[arow * 16 + (ko ^ (arow & 7))];
#pragma unroll
        for (int ni = 0; ni < 8; ++ni) {
            int n = ni * 16 + l16;
            bf16x8 bf = Wv[n * 16 + (ko ^ (n & 7))];
            acc8[ni] = __builtin_amdgcn_mfma_f32_16x16x32_bf16(af, bf, acc8[ni], 0, 0, 0);
        }
    }
#pragma unroll
    for (int r = 0; r < 4; ++r) {
        int lrow = wave * 16 + quad * 4 + r;
        int grow = row0 + lrow;
        int l = grow % NL;
#pragma unroll
        for (int ni = 0; ni < 8; ++ni) {
            int col = ni * 16 + l16;
            float nhv = fast_tanh(posPart[l * ND + col] + acc8[ni][r]);
            NHS[lrow * 136 + col] = __float2bfloat16(nhv);
        }
    }
    __syncthreads(); // NHS complete, WS free
    // ---- GEMM2: 4 chunks of 128 cols; chunk ch == k-segment ch ----
    for (int ch = 0; ch < 4; ++ch) {
#pragma unroll
        for (int it = 0; it < 8; ++it) {
            int id = it * 256 + tid;
            int row = id >> 4, c = id & 15, gc = c ^ (row & 7);
            gld_lds16((const char*)glu_t + ((size_t)(ch * ND + row) * 16 + gc) * 16,
                      (char*)WS + (size_t)(it * 256 + wave * 64) * 16);
        }
        __syncthreads();
#pragma unroll
        for (int ni = 0; ni < 8; ++ni) acc8[ni] = (f32x4){0.f, 0.f, 0.f, 0.f};
#pragma unroll
        for (int kk = 0; kk < 4; ++kk) {
            int ko = kk * 4 + quad;
            bf16x8 af = Nv[arow * 17 + ko]; // padded, no swizzle
#pragma unroll
            for (int ni = 0; ni < 8; ++ni) {
                int n = ni * 16 + l16;
                bf16x8 bf = Wv[n * 16 + (ko ^ (n & 7))];
                acc8[ni] = __builtin_amdgcn_mfma_f32_16x16x32_bf16(af, bf, acc8[ni], 0, 0, 0);
            }
        }
#pragma unroll
        for (int r = 0; r < 4; ++r) {
            float s = 0.f;
#pragma unroll
            for (int ni = 0; ni < 8; ++ni) {
                int col = ni * 16 + l16;
                s += sigm_fast(acc8[ni][r] + glu1_b[ch * ND + col]) * w2[col * 4 + ch];
            }
#pragma unroll
            for (int off = 1; off < 16; off <<= 1) s += __shfl_xor(s, off);
            if (l16 == 0) {
                int lrow = wave * 16 + quad * 4 + r;
                int grow = row0 + lrow;
                float a = alphaS[lrow * 4 + ch];
                beta_out[(size_t)grow * 4 + ch] = s * (0.5f + a) * (float)mask[grow];
            }
        }
        __syncthreads();
    }
}

// ---------------- K2: loss (lens inline, atomic accumulate) ----------------
__global__ void k_loss(const float* __restrict__ beta, const int* __restrict__ mask,
                       float* __restrict__ loss_out) {
    int b = blockIdx.x;
    int t = threadIdx.x; // 64
    float mv = (t < NL) ? (float)mask[b * NL + t] : 0.f;
    float msum = mv;
    for (int off = 32; off >= 1; off >>= 1) msum += __shfl_xor(msum, off);
    float lens = msum - 5.0f; // LENGTH=5
    float bk[NK] = {0.f, 0.f, 0.f, 0.f};
    if (t < NL) {
#pragma unroll
        for (int k = 0; k < NK; ++k) bk[k] = beta[((size_t)b * NL + t) * NK + k];
    }
    float nb[NK];
#pragma unroll
    for (int k = 0; k < NK; ++k) {
        float v = bk[k] * bk[k];
        for (int off = 32; off >= 1; off >>= 1) v += __shfl_xor(v, off);
        nb[k] = bk[k] / fmaxf(sqrtf(v), 1e-12f);
    }
    float sim = 0.f;
#pragma unroll
    for (int i = 0; i < NK; ++i) {
#pragma unroll
        for (int j = 0; j < NK; ++j) {
            if (j > i) {
                float p = nb[i] * nb[j];
                for (int off = 32; off >= 1; off >>= 1) p += __shfl_xor(p, off);
                sim += fabsf(p);
            }
        }
    }
    sim *= (2.0f / (NK * (NK - 1)));
    if (t == 0) atomicAdd(loss_out, sigm_prec(sim * lens) * 0.01f); // BETA
}

// ---------------- K3: select -> bf16 (2 b per block) ----------------
__global__ __launch_bounds__(256) void k_select(
    const float* __restrict__ beta, const float* __restrict__ hidden,
    __hip_bfloat16* __restrict__ selb) {
    int b = blockIdx.x * 2 + (threadIdx.x >> 7);
    int d = threadIdx.x & 127;
    float a0 = 0.f, a1 = 0.f, a2 = 0.f, a3 = 0.f;
    for (int l = 0; l < NL; ++l) {
        float h = hidden[((size_t)b * NL + l) * ND + d];
        const float* bp = &beta[((size_t)b * NL + l) * NK];
        a0 = fmaf(bp[0], h, a0);
        a1 = fmaf(bp[1], h, a1);
        a2 = fmaf(bp[2], h, a2);
        a3 = fmaf(bp[3], h, a3);
    }
    selb[((size_t)b * NK + 0) * ND + d] = __float2bfloat16(a0);
    selb[((size_t)b * NK + 1) * ND + d] = __float2bfloat16(a1);
    selb[((size_t)b * NK + 2) * ND + d] = __float2bfloat16(a2);
    selb[((size_t)b * NK + 3) * ND + d] = __float2bfloat16(a3);
}

// ---------------- K4: big GEMM  C[1024,NPAD2] = selb @ bnv^T, LDS-staged bf16 MFMA ----------------
__global__ __launch_bounds__(256) void k_gemm(
    const __hip_bfloat16* __restrict__ selb, const __hip_bfloat16* __restrict__ bn,
    float* __restrict__ scores, float* __restrict__ maxs) {
    __shared__ __hip_bfloat16 As[128 * 128]; // 32 KB
    __shared__ __hip_bfloat16 Bs[128 * 128]; // 32 KB
    int bm0 = blockIdx.y * 128;
    int nbase = blockIdx.x * (128 * GEMM_NT);
    int tid = threadIdx.x;
    int wave = tid >> 6, lane = tid & 63;
    int l16 = lane & 15, quad = lane >> 4;
    int m_loc = (wave >> 1) * 64;
    int n_loc = (wave & 1) * 64;

#pragma unroll
    for (int it = 0; it < 8; ++it) {
        int id = it * 256 + tid;
        int row = id >> 4, c = id & 15, gc = c ^ (row & 7);
        gld_lds16((const char*)selb + ((size_t)(bm0 + row) * 16 + gc) * 16,
                  (char*)As + (size_t)(it * 256 + wave * 64) * 16);
    }

    const bf16x8* Av = (const bf16x8*)As;
    const bf16x8* Bv = (const bf16x8*)Bs;

    for (int nt = 0; nt < GEMM_NT; ++nt) {
        int bn0 = nbase + nt * 128;
#pragma unroll
        for (int it = 0; it < 8; ++it) {
            int id = it * 256 + tid;
            int row = id >> 4, c = id & 15, gc = c ^ (row & 7);
            gld_lds16((const char*)bn + ((size_t)(bn0 + row) * 16 + gc) * 16,
                      (char*)Bs + (size_t)(it * 256 + wave * 64) * 16);
        }
        __syncthreads();

        f32x4 acc[4][4];
#pragma unroll
        for (int mi = 0; mi < 4; ++mi)
#pragma unroll
            for (int ni = 0; ni < 4; ++ni) acc[mi][ni] = (f32x4){0.f, 0.f, 0.f, 0.f};

#pragma unroll
        for (int kk = 0; kk < 4; ++kk) {
            int ko = kk * 4 + quad;
            bf16x8 afr[4], bfr[4];
#pragma unroll
            for (int mi = 0; mi < 4; ++mi) {
                int row = m_loc + mi * 16 + l16;
                afr[mi] = Av[row * 16 + (ko ^ (row & 7))];
            }
#pragma unroll
            for (int ni = 0; ni < 4; ++ni) {
                int row = n_loc + ni * 16 + l16;
                bfr[ni] = Bv[row * 16 + (ko ^ (row & 7))];
            }
#pragma unroll
            for (int mi = 0; mi < 4; ++mi)
#pragma unroll
                for (int ni = 0; ni < 4; ++ni)
                    acc[mi][ni] = __builtin_amdgcn_mfma_f32_16x16x32_bf16(
                        afr[mi], bfr[ni], acc[mi][ni], 0, 0, 0);
        }

#pragma unroll
        for (int mi = 0; mi < 4; ++mi) {
            int m_base = bm0 + m_loc + mi * 16;
            int bidx = (m_base >> 2) + quad;
#pragma unroll
            for (int ni = 0; ni < 4; ++ni) {
                int n = bn0 + n_loc + ni * 16 + l16;
                if (n < NVm1) {
                    float mx = acc[mi][ni][0];
#pragma unroll
                    for (int r = 0; r < 4; ++r) {
                        float val = acc[mi][ni][r];
                        scores[(size_t)r * NB * NVm1 + (size_t)bidx * NVm1 + n] = val;
                        mx = fmaxf(mx, val);
                    }
                    maxs[(size_t)bidx * NVm1 + n] = mx;
                }
            }
        }
        __syncthreads();
    }
}

extern "C" void kernel_launch(void* const* d_in, const int* in_sizes, int n_in,
                              void* d_out, int out_size, void* d_ws, size_t ws_size,
                              hipStream_t stream) {
    const float* hidden  = (const float*)d_in[0];
    const int*   mask    = (const int*)d_in[1];
    const float* pos_emb = (const float*)d_in[2];
    const float* w1      = (const float*)d_in[3];
    const float* w2      = (const float*)d_in[4];
    const float* glu1_w  = (const float*)d_in[5];
    const float* glu1_b  = (const float*)d_in[6];
    const float* att_w1  = (const float*)d_in[7];
    const float* att_w2  = (const float*)d_in[8];
    const float* att_v   = (const float*)d_in[9];
    const float* emb     = (const float*)d_in[10];

    float* out      = (float*)d_out;
    float* max_out  = out;                                   // [B, NVm1]
    float* loss_out = out + (size_t)NB * NVm1;               // scalar
    float* scores   = out + (size_t)NB * NVm1 + 1;           // [K, B, NVm1]

    char* w = (char*)d_ws;
    auto alloc = [&](size_t bytes) {
        char* p = w;
        w += (bytes + 255) & ~(size_t)255;
        return p;
    };
    float* posPart = (float*)alloc((size_t)NL * ND * 4);
    float* hs      = (float*)alloc((size_t)NB * ND * 4);
    float* betav   = (float*)alloc((size_t)ROWS * NK * 4);
    __hip_bfloat16* XbG     = (__hip_bfloat16*)alloc((size_t)ROWS * ND * 2);
    __hip_bfloat16* w1h_t   = (__hip_bfloat16*)alloc((size_t)ND * ND * 2);
    __hip_bfloat16* attw2_t = (__hip_bfloat16*)alloc((size_t)ND * ND * 2);
    __hip_bfloat16* glu_t   = (__hip_bfloat16*)alloc((size_t)512 * ND * 2);
    __hip_bfloat16* selb    = (__hip_bfloat16*)alloc((size_t)MROWS * ND * 2);
    __hip_bfloat16* bnv     = (__hip_bfloat16*)alloc((size_t)NPAD2 * ND * 2);

    k_prep<<<G_TOT, 256, 0, stream>>>(hidden, mask, pos_emb, w1, att_w2, glu1_w, emb,
                                      hs, posPart, XbG, w1h_t, attw2_t, glu_t, bnv, loss_out);
    k_mega<<<ROWS / MR, 256, 0, stream>>>(XbG, w1h_t, attw2_t, glu_t, hs, att_w1,
                                          att_v, posPart, glu1_b, w2, mask, betav);
    k_loss<<<NB, 64, 0, stream>>>(betav, mask, loss_out);
    k_select<<<NB / 2, 256, 0, stream>>>(betav, hidden, selb);
    k_gemm<<<dim3(NPAD2 / (128 * GEMM_NT), MROWS / 128), 256, 0, stream>>>(selb, bnv, scores, max_out);
}